// Round 8
// baseline (45.600 us; speedup 1.0000x reference)
//
#include <hip/hip_runtime.h>
#include <stdint.h>

// Problem constants
#define BB 1024
#define MM 128
#define KK 32
#define NEDGE (BB * MM * KK)   // 4194304
#define BPB 4                  // blocks per batch
#define ROWS_PER_WAVE (MM / (4 * BPB))  // 8

typedef unsigned int uint2v __attribute__((ext_vector_type(2)));

// ---- keep-min lane masks (compile-time) ----
// phase 1, k0: lanes 0-31 asc, 32-63 desc (blocks A,B); k1 uses ~p1mask (C desc, D asc)
static constexpr unsigned long long p1mask(int size, int stride) {
    unsigned long long m = 0;
    for (int l = 0; l < 64; ++l) {
        int g = l & 31;
        bool up = (((g & size) == 0) != (l >= 32));
        bool keep = (((g & stride) == 0) == up);
        if (keep) m |= 1ull << l;
    }
    return m;
}
// dual clean: lower half asc, upper half desc
static constexpr unsigned long long dualmask(int stride) {
    unsigned long long m = 0;
    for (int l = 0; l < 64; ++l) {
        int g = l & 31;
        bool km = (l < 32) ? ((g & stride) == 0) : ((g & stride) != 0);
        if (km) m |= 1ull << l;
    }
    return m;
}
// final clean: asc, duplicated halves
static constexpr unsigned long long cleanmask(int stride) {
    unsigned long long m = 0;
    for (int l = 0; l < 64; ++l) {
        int g = l & 31;
        if ((g & stride) == 0) m |= 1ull << l;
    }
    return m;
}

#define DPP1 "quad_perm:[1,0,3,2] row_mask:0xf bank_mask:0xf"
#define DPP2 "quad_perm:[2,3,0,1] row_mask:0xf bank_mask:0xf"
#define DPP8 "row_ror:8 row_mask:0xf bank_mask:0xf"

// ---- fused dual-key DPP compare-exchange, tied in-place (6 VALU, 4 regs) ----
// k0 keeps p1mask(S,ST); k1 keeps ~p1mask(S,ST). The k0/k1 alternation covers
// the 2-wait-state DPP read-after-VALU-write hazard by construction; NOPSTR
// guards entry when the previous writer of k0 is <2 instructions back.
#define CEX2_DPP(DPPSTR, NOPSTR, S, ST)                                      \
  { constexpr unsigned long long M0c = p1mask(S, ST);                        \
    constexpr unsigned long long M1c = ~p1mask(S, ST);                       \
    unsigned t0, t1;                                                         \
    asm(NOPSTR                                                               \
        "v_min_u32_dpp %2, %0, %0 " DPPSTR "\n\t"                            \
        "v_max_u32_dpp %3, %0, %0 " DPPSTR "\n\t"                            \
        "v_cndmask_b32 %0, %3, %2, %4\n\t"                                   \
        "v_min_u32_dpp %2, %1, %1 " DPPSTR "\n\t"                            \
        "v_max_u32_dpp %3, %1, %1 " DPPSTR "\n\t"                            \
        "v_cndmask_b32 %1, %3, %2, %5"                                       \
        : "+v"(k0), "+v"(k1), "=&v"(t0), "=&v"(t1)                           \
        : "s"(M0c), "s"(M1c)); }

// dual-key swizzle compare-exchange (partner fetch on LDS pipe; compiler
// handles hazards/waitcnt for the builtins; final selects in-place)
#define CEX2_SW(ST, S)                                                       \
  { constexpr unsigned long long M0c = p1mask(S, ST);                        \
    constexpr unsigned long long M1c = ~p1mask(S, ST);                       \
    unsigned p0 = (unsigned)__builtin_amdgcn_ds_swizzle((int)k0, ((ST) << 10) | 0x1F); \
    unsigned p1 = (unsigned)__builtin_amdgcn_ds_swizzle((int)k1, ((ST) << 10) | 0x1F); \
    unsigned mn0 = __builtin_elementwise_min(k0, p0);                        \
    unsigned mx0 = __builtin_elementwise_max(k0, p0);                        \
    unsigned mn1 = __builtin_elementwise_min(k1, p1);                        \
    unsigned mx1 = __builtin_elementwise_max(k1, p1);                        \
    asm("v_cndmask_b32 %0, %1, %2, %3" : "=v"(k0) : "v"(mx0), "v"(mn0), "s"(M0c)); \
    asm("v_cndmask_b32 %0, %1, %2, %3" : "=v"(k1) : "v"(mx1), "v"(mn1), "s"(M1c)); }

// single-stream cex, tied in-place: s_nop-guarded DPP or swizzle
template<int ST, unsigned long long MASK>
static __device__ __forceinline__ void cex1(unsigned& k) {
    if constexpr (ST == 1 || ST == 2 || ST == 8) {
        unsigned t0, t1;
        if constexpr (ST == 1) {
            asm("s_nop 1\n\t"
                "v_min_u32_dpp %1, %0, %0 " DPP1 "\n\t"
                "v_max_u32_dpp %2, %0, %0 " DPP1 "\n\t"
                "v_cndmask_b32 %0, %2, %1, %3"
                : "+v"(k), "=&v"(t0), "=&v"(t1) : "s"(MASK));
        } else if constexpr (ST == 2) {
            asm("s_nop 1\n\t"
                "v_min_u32_dpp %1, %0, %0 " DPP2 "\n\t"
                "v_max_u32_dpp %2, %0, %0 " DPP2 "\n\t"
                "v_cndmask_b32 %0, %2, %1, %3"
                : "+v"(k), "=&v"(t0), "=&v"(t1) : "s"(MASK));
        } else {
            asm("s_nop 1\n\t"
                "v_min_u32_dpp %1, %0, %0 " DPP8 "\n\t"
                "v_max_u32_dpp %2, %0, %0 " DPP8 "\n\t"
                "v_cndmask_b32 %0, %2, %1, %3"
                : "+v"(k), "=&v"(t0), "=&v"(t1) : "s"(MASK));
        }
    } else {
        unsigned p = (unsigned)__builtin_amdgcn_ds_swizzle((int)k, (ST << 10) | 0x1F);
        unsigned mn = __builtin_elementwise_min(k, p);
        unsigned mx = __builtin_elementwise_max(k, p);
        asm("v_cndmask_b32 %0, %1, %2, %3" : "=v"(k) : "v"(mx), "v"(mn), "s"(MASK));
    }
}

// min over {v[l], v[l^32]} — bitonic split across the 32-lane halves
static __device__ __forceinline__ unsigned minxor32(unsigned k) {
#if __has_builtin(__builtin_amdgcn_permlane32_swap)
    uint2v s = __builtin_amdgcn_permlane32_swap(k, k, false, false);
    return __builtin_elementwise_min(s.x, s.y);
#else
    unsigned p = (unsigned)__shfl_xor((int)k, 32, 64);
    return __builtin_elementwise_min(k, p);
#endif
}

// grid = BB*BPB blocks of 256 threads; each wave handles 8 rows.
// Per row: 128 candidates (2/lane), key = (f32bits(max(d2,0)) & ~0x7F) | j.
// Network: sort A asc|B desc (k0) and C desc|D asc (k1); min(k0,k1) is a
// shuffle-free bitonic split; dual-clean; permlane split; final clean.
__global__ __launch_bounds__(256, 4) void knn_edges_kernel(const float* __restrict__ pos,
                                                           float* __restrict__ out) {
    __shared__ float px[MM], py[MM], pz[MM], sqs[MM];
    const int blk = blockIdx.x;
    const int b = blk >> 2;            // blk / BPB
    const int sub = blk & (BPB - 1);
    const int tid = threadIdx.x;

    if (tid < MM) {
        const float* p = pos + (size_t)(b * MM + tid) * 3;
        float x = p[0], y = p[1], z = p[2];
        px[tid] = x; py[tid] = y; pz[tid] = z;
        sqs[tid] = __fadd_rn(__fadd_rn(__fmul_rn(x, x), __fmul_rn(y, y)), __fmul_rn(z, z));
    }
    __syncthreads();

    const int wave = tid >> 6;
    const int lane = tid & 63;
    const int r = lane & 31;
    const bool hi = lane >= 32;

    // per-lane candidate coordinates, hoisted across the row loop
    const int j0 = lane, j1 = lane + 64;
    const float xa = px[j0], ya = py[j0], za = pz[j0], qa = sqs[j0];
    const float xb = px[j1], yb = py[j1], zb = pz[j1], qb = sqs[j1];

    const int row0 = sub * (MM / BPB) + wave * ROWS_PER_WAVE;
    const int node0 = b * MM + row0;
    const float fbase = (float)(b * MM);   // exact in fp32

    // output streams (3 stores/lane/row):
    //  lanes <32 : pA=src (KK), pB=vec.x (3KK), pC=vec.y (3KK)
    //  lanes >=32: pA=dst (KK), pB=vec.z (3KK), pC=weight (KK)
    float* const vecbase = out + 3 * (size_t)NEDGE;
    const long e0 = (long)node0 * KK + r;
    float* pA = hi ? out + (size_t)NEDGE + e0 : out + e0;
    float* pB = vecbase + e0 * 3 + (hi ? 2 : 0);
    float* pC = hi ? out + 2 * (size_t)NEDGE + e0 : vecbase + e0 * 3 + 1;
    const int sC = hi ? KK : KK * 3;

    float fnode = (float)node0;

    for (int i = row0; i < row0 + ROWS_PER_WAVE; ++i) {
        const float xi = px[i], yi = py[i], zi = pz[i], qi = sqs[i];

        // ---- candidate keys ----
        float dot0 = fmaf(xi, xa, fmaf(yi, ya, zi * za));
        float d20 = fmaxf((qi + qa) - 2.0f * dot0, 0.0f);
        unsigned k0 = (__float_as_uint(d20) & 0xFFFFFF80u) | (unsigned)j0;

        float dot1 = fmaf(xi, xb, fmaf(yi, yb, zi * zb));
        float d21 = fmaxf((qi + qb) - 2.0f * dot1, 0.0f);
        unsigned k1 = (__float_as_uint(d21) & 0xFFFFFF80u) | (unsigned)j1;

        // ---- phase 1: sort four 32-blocks; k0: A asc|B desc, k1: C desc|D asc
        CEX2_DPP(DPP1, "s_nop 0\n\t", 2, 1)
        CEX2_DPP(DPP2, "",            4, 2)
        CEX2_DPP(DPP1, "",            4, 1)
        CEX2_SW(4,                    8)
        CEX2_DPP(DPP2, "s_nop 0\n\t", 8, 2)
        CEX2_DPP(DPP1, "",            8, 1)
        CEX2_DPP(DPP8, "",            16, 8)
        CEX2_SW(4,                    16)
        CEX2_DPP(DPP2, "s_nop 0\n\t", 16, 2)
        CEX2_DPP(DPP1, "",            16, 1)
        CEX2_SW(16,                   32)
        CEX2_DPP(DPP8, "s_nop 0\n\t", 32, 8)
        CEX2_SW(4,                    32)
        CEX2_DPP(DPP2, "s_nop 0\n\t", 32, 2)
        CEX2_DPP(DPP1, "",            32, 1)

        // ---- merge 1: shuffle-free bitonic split (A∪C | B∪D) ----
        unsigned c = __builtin_elementwise_min(k0, k1);

        // ---- dual clean: lower 32 asc, upper 32 desc ----
        cex1<16, dualmask(16)>(c);
        cex1<8,  dualmask(8)>(c);
        cex1<4,  dualmask(4)>(c);
        cex1<2,  dualmask(2)>(c);
        cex1<1,  dualmask(1)>(c);

        // ---- merge 2: split across halves (duplicated result) ----
        unsigned m = minxor32(c);

        // ---- final clean ascending ----
        cex1<16, cleanmask(16)>(m);
        cex1<8,  cleanmask(8)>(m);
        cex1<4,  cleanmask(4)>(m);
        cex1<2,  cleanmask(2)>(m);
        cex1<1,  cleanmask(1)>(m);

        // ---- epilogue: rank r duplicated across halves; 3 stores/lane ----
        const bool taken = m < 0x41C80000u;   // d2 < 25.0
        const int j = (int)(m & 127u);
        const int sel = taken ? j : i;

        float dxv = __fsub_rn(px[sel], xi);
        float dyv = __fsub_rn(py[sel], yi);
        float dzv = __fsub_rn(pz[sel], zi);
        // w = |vec|; sqrt(0)=0 covers both !taken and self, no conditional
        float w = sqrtf(fmaf(dzv, dzv, fmaf(dyv, dyv, dxv * dxv)));

        const float fsrc = fbase + (float)sel;   // exact integer in fp32

        *pA = hi ? fnode : fsrc;
        *pB = hi ? dzv : dxv;
        *pC = hi ? w : dyv;
        pA += KK; pB += KK * 3; pC += sC;
        fnode += 1.0f;
    }
}

extern "C" void kernel_launch(void* const* d_in, const int* in_sizes, int n_in,
                              void* d_out, int out_size, void* d_ws, size_t ws_size,
                              hipStream_t stream) {
    const float* pos = (const float*)d_in[0];
    float* out = (float*)d_out;
    hipLaunchKernelGGL(knn_edges_kernel, dim3(BB * BPB), dim3(256), 0, stream, pos, out);
}